// Round 11
// baseline (4278.377 us; speedup 1.0000x reference)
//
#include <hip/hip_runtime.h>

typedef unsigned short u16;
typedef unsigned int u32;
typedef short bf16x8 __attribute__((ext_vector_type(8)));
typedef float f32x4 __attribute__((ext_vector_type(4)));

#define NB 128
#define NL 400
#define NT 30
#define NE 300
#define KE 320
#define NHE 512
#define NHD 512
#define NA 512
#define NV 20000
#define NVP 20096
#define K1 1024
#define N1 2048
#define NW 2048
#define OUTW (NV+NL)
#define NBLK 1024

static __device__ __forceinline__ u16 f2b(float x){ u32 u=__float_as_uint(x); u += 0x7FFFu + ((u>>16)&1u); return (u16)(u>>16); }
static __device__ __forceinline__ float b2f(u16 h){ return __uint_as_float(((u32)h)<<16); }
static __device__ __forceinline__ float fsig(float x){ return 1.f/(1.f+__expf(-x)); }
static __device__ __forceinline__ float ftanh(float x){ return 1.f - 2.f/(__expf(2.f*x)+1.f); }

static __device__ __forceinline__ float atL(const float* p){ return __hip_atomic_load(p, __ATOMIC_RELAXED, __HIP_MEMORY_SCOPE_AGENT); }
static __device__ __forceinline__ u32   atLu(const u32* p){ return __hip_atomic_load(p, __ATOMIC_RELAXED, __HIP_MEMORY_SCOPE_AGENT); }
static __device__ __forceinline__ void  atS(float* p, float v){ __hip_atomic_store(p, v, __ATOMIC_RELAXED, __HIP_MEMORY_SCOPE_AGENT); }
static __device__ __forceinline__ void  atSu(u32* p, u32 v){ __hip_atomic_store(p, v, __ATOMIC_RELAXED, __HIP_MEMORY_SCOPE_AGENT); }

static __device__ __forceinline__ void gll16(const u16* g, u16* l){
  __builtin_amdgcn_global_load_lds((const __attribute__((address_space(1))) void*)g,
                                   (__attribute__((address_space(3))) void*)l, 16, 0, 0);
}

// Pipelined 128x128 tile GEMM: A[M,K] x B[N,K] row-major bf16, f32 accum. 256 thr.
static __device__ __forceinline__ void gemm_pipe(const u16* A, int lda, const u16* Bm, int ldb,
                                                 int K, u16* ls, f32x4 (&acc)[4][4]){
  const int tid = threadIdx.x;
  const int wave = tid>>6, lane = tid&63;
  const int srow = lane>>2;
  const int sko = (((lane&3) ^ ((lane>>3)&3)))*8;
  const int wm = wave>>1, wn = wave&1;
#pragma unroll
  for (int i=0;i<4;i++)
#pragma unroll
    for (int j=0;j<4;j++)
#pragma unroll
      for (int q=0;q<4;q++) acc[i][j][q] = 0.f;
  const int nk = K>>5;
  auto issue = [&](int kt, int bsel){
    u16* dA = ls + bsel*8192;
    u16* dB = dA + 4096;
#pragma unroll
    for (int i=0;i<2;i++){
      const int c = wave*2+i;
      const int row = c*16 + srow;
      gll16(A + (size_t)row*lda + kt + sko, dA + c*512);
      gll16(Bm + (size_t)row*ldb + kt + sko, dB + c*512);
    }
  };
  issue(0, 0);
  issue(nk>1 ? 32 : 0, 1);
  for (int it=0; it<nk; ++it){
    asm volatile("s_waitcnt vmcnt(4)" ::: "memory");
    __builtin_amdgcn_s_barrier();
    const u16* lsA = ls + (it&1)*8192;
    const u16* lsB = lsA + 4096;
    const int rsel = (lane&15)*32 + (((lane>>4) ^ ((lane>>1)&3))*8);
    bf16x8 aF[4], bF[4];
#pragma unroll
    for (int mi=0;mi<4;mi++) aF[mi] = *(const bf16x8*)(lsA + (wm*64+mi*16)*32 + rsel);
#pragma unroll
    for (int nj=0;nj<4;nj++) bF[nj] = *(const bf16x8*)(lsB + (wn*64+nj*16)*32 + rsel);
#pragma unroll
    for (int mi=0;mi<4;mi++)
#pragma unroll
      for (int nj=0;nj<4;nj++)
        acc[mi][nj] = __builtin_amdgcn_mfma_f32_16x16x32_bf16(aF[mi], bF[nj], acc[mi][nj], 0,0,0);
    __builtin_amdgcn_s_barrier();
    issue(it+2 < nk ? (it+2)*32 : 0, it&1);
  }
  asm volatile("s_waitcnt vmcnt(0)" ::: "memory");
  __builtin_amdgcn_s_barrier();
}

// ---------------- setup kernels ----------------

__global__ __launch_bounds__(256) void k_conv_flat(const float* __restrict__ s, u16* __restrict__ d, long n){
  long i = (long)blockIdx.x*256 + threadIdx.x;
  const long st = (long)gridDim.x*256;
  for (; i<n; i+=st) d[i] = f2b(s[i]);
}

__global__ __launch_bounds__(256) void k_convpad(const float* __restrict__ s, u16* __restrict__ d,
                                                 int srows, int sk, int dk, long total){
  long i = (long)blockIdx.x*256 + threadIdx.x;
  const long st = (long)gridDim.x*256;
  for (; i<total; i+=st){
    int r = (int)(i / dk), k = (int)(i - (long)r*dk);
    d[i] = (r < srows && k < sk) ? f2b(s[(size_t)r*sk + k]) : (u16)0;
  }
}

__global__ __launch_bounds__(512) void k_transpose(const float* __restrict__ enc, u16* __restrict__ encT){
  const int b = blockIdx.y, jt = blockIdx.x;
  __shared__ float tile[16][33];
  const int tid = threadIdx.x;
  for (int lt=0; lt<25; lt++){
    {
      int l = lt*16 + (tid>>5), j = jt*32 + (tid&31);
      tile[tid>>5][tid&31] = enc[((size_t)b*NL + l)*512 + j];
    }
    __syncthreads();
    {
      int jw = tid>>4, lw = tid&15;
      encT[((size_t)b*512 + jt*32 + jw)*NL + lt*16 + lw] = f2b(tile[lw][jw]);
    }
    __syncthreads();
  }
}

// W1[2048][1024]: rows 0..1024 [Whh_rz|Wih_ctx_rz]; 1024..1536 [Whh_n|0]; 1536..2048 [0|Wih_ctx_n]
__global__ __launch_bounds__(256) void k_build_w1(const float* __restrict__ Whh, const float* __restrict__ Wih, u16* __restrict__ d){
  int idx = blockIdx.x*256 + threadIdx.x;
  if (idx >= N1*K1) return;
  int n = idx >> 10, k = idx & 1023;
  float v = 0.f;
  if (n < 1024)       v = (k<512) ? Whh[(size_t)n*512 + k] : Wih[(size_t)n*812 + 300 + (k-512)];
  else if (n < 1536)  v = (k<512) ? Whh[(size_t)n*512 + k] : 0.f;
  else                v = (k<512) ? 0.f : Wih[(size_t)(n-512)*812 + 300 + (k-512)];
  d[idx] = f2b(v);
}

__global__ __launch_bounds__(256) void k_build_w2(const float* __restrict__ Wr, u16* __restrict__ d){
  int idx = blockIdx.x*256 + threadIdx.x;
  if (idx >= 512*K1) return;
  int r = idx >> 10, k = idx & 1023;
  float v = (k<512) ? Wr[(size_t)r*1324 + 812 + k] : Wr[(size_t)r*1324 + 300 + (k-512)];
  d[idx] = f2b(v);
}

__global__ __launch_bounds__(256) void k_build_wemb(const float* __restrict__ Wih, const float* __restrict__ Wr, u16* __restrict__ d){
  int idx = blockIdx.x*256 + threadIdx.x;
  if (idx >= NW*KE) return;
  int n = idx / KE, k = idx - n*KE;
  float v = 0.f;
  if (k < NE) v = (n < 1536) ? Wih[(size_t)n*812 + k] : Wr[(size_t)(n-1536)*1324 + k];
  d[idx] = f2b(v);
}

__global__ __launch_bounds__(256) void k_build_xemb(const int* __restrict__ tgt, const float* __restrict__ embed, u16* __restrict__ d){
  int idx = blockIdx.x*256 + threadIdx.x;
  if (idx >= NT*NB*KE) return;
  int row = idx / KE, k = idx - row*KE;
  int t = row >> 7, b = row & 127;
  u16 hv = 0;
  if (k < NE){
    int w = 2;
    if (t > 0){ w = tgt[b*NT + t-1]; if ((u32)w >= (u32)NV) w = 1; }
    hv = f2b(embed[(size_t)w*NE + k]);
  }
  d[idx] = hv;
}

__global__ __launch_bounds__(256) void k_init(const float* __restrict__ s_in, float* __restrict__ sbuf0, u16* __restrict__ x1A){
  int idx = blockIdx.x*256 + threadIdx.x;
  if (idx < 65536){
    int b = idx>>9, j = idx&511;
    float v = s_in[idx];
    sbuf0[idx] = v;
    x1A[(size_t)b*K1 + j] = f2b(v);
  } else if (idx < 131072){
    int k = idx - 65536;
    int b = k>>9, j = k&511;
    x1A[(size_t)b*K1 + 512 + j] = 0;
  }
}

__global__ __launch_bounds__(256) void k_encproj(const u16* __restrict__ A, const u16* __restrict__ Bw, u16* __restrict__ C){
  __shared__ __align__(16) u16 ls[16384];
  const int n0 = blockIdx.x*128, m0 = blockIdx.y*128;
  f32x4 acc[4][4];
  gemm_pipe(A + (size_t)m0*512, 512, Bw + (size_t)n0*512, 512, 512, ls, acc);
  const int tid=threadIdx.x, wave=tid>>6, lane=tid&63, wm=wave>>1, wn=wave&1;
#pragma unroll
  for (int mi=0;mi<4;mi++)
#pragma unroll
    for (int nj=0;nj<4;nj++)
#pragma unroll
      for (int q=0;q<4;q++){
        int r = m0 + wm*64 + mi*16 + (lane>>4)*4 + q;
        int c = n0 + wn*64 + nj*16 + (lane&15);
        C[(size_t)r*512 + c] = f2b(acc[mi][nj][q]);
      }
}

__global__ __launch_bounds__(256) void k_gemm_emb(const u16* __restrict__ Xe, const u16* __restrict__ We, float* __restrict__ gre){
  __shared__ __align__(16) u16 ls[16384];
  const int n0 = blockIdx.x*128, m0 = blockIdx.y*128;
  f32x4 acc[4][4];
  gemm_pipe(Xe + (size_t)m0*KE, KE, We + (size_t)n0*KE, KE, KE, ls, acc);
  const int tid=threadIdx.x, wave=tid>>6, lane=tid&63, wm=wave>>1, wn=wave&1;
#pragma unroll
  for (int mi=0;mi<4;mi++)
#pragma unroll
    for (int nj=0;nj<4;nj++)
#pragma unroll
      for (int q=0;q<4;q++){
        int r = m0 + wm*64 + mi*16 + (lane>>4)*4 + q;
        int c = n0 + wn*64 + nj*16 + (lane&15);
        gre[(size_t)r*NW + c] = acc[mi][nj][q];
      }
}

// ---------------- persistent pass-A kernel (recurrence only) ----------------

struct KP {
  const float *bih, *bhh, *attb, *attv, *copyW, *copyb;
  const int   *src;
  const u16   *Wsb, *eproj, *encT, *W1;
  const float *gre;
  float *gA, *gB, *sbufA, *sbufB, *e, *ctx_ws, *attn_all, *pcb_all;
  u16   *x1A;
  u32   *slots, *gen;
};

// Fence-free flag-array barrier (1024 blocks). Scanner: block 0, 64 lanes x 16
// slots. Distributed gen lines: 16 pollers per 64B line.
static __device__ __forceinline__ void gbar(const KP& p, u32& ep){
  ++ep;
  asm volatile("s_waitcnt vmcnt(0)" ::: "memory");
  __syncthreads();
  if (threadIdx.x==0)
    atSu(p.slots + blockIdx.x, ep);
  if (blockIdx.x==0){
    if (threadIdx.x < 64){
      const u32* sl = p.slots + threadIdx.x*16;
      for (;;){
        u32 mn = 0xFFFFFFFFu;
#pragma unroll
        for (int j=0;j<16;j++){
          u32 v = atLu(sl+j);
          mn = v<mn ? v : mn;
        }
        if (__all(mn >= ep)) break;
        __builtin_amdgcn_s_sleep(4);
      }
      atSu(p.gen + threadIdx.x*16, ep);   // 64 lines, 64B stride
    }
  } else if (threadIdx.x==0){
    const u32* gp = p.gen + (blockIdx.x>>4)*16;
    while (atLu(gp) < ep) __builtin_amdgcn_s_sleep(4);
  }
  asm volatile("" ::: "memory");
  __syncthreads();
}

// P1: g = x1A[t] @ W1^T, 2-way K-split. u 0..31: ks=u&1, ntile=u>>1
static __device__ void ph_g1(const KP& p, char* sm, int u, int t){
  u16* ls = (u16*)sm;
  const int ks = u&1, n0 = (u>>1)*128;
  const u16* A  = p.x1A + (size_t)t*NB*K1 + ks*512;
  const u16* Bm = p.W1 + (size_t)n0*K1 + ks*512;
  f32x4 acc[4][4];
  gemm_pipe(A, K1, Bm, K1, 512, ls, acc);
  float* gd = ks ? p.gB : p.gA;
  const int tid=threadIdx.x, wave=tid>>6, lane=tid&63, wm=wave>>1, wn=wave&1;
#pragma unroll
  for (int mi=0;mi<4;mi++)
#pragma unroll
    for (int nj=0;nj<4;nj++)
#pragma unroll
      for (int q=0;q<4;q++){
        int r = wm*64 + mi*16 + (lane>>4)*4 + q;
        int c = n0 + wn*64 + nj*16 + (lane&15);
        atS(gd + (size_t)r*N1 + c, acc[mi][nj][q]);
      }
}

// P2: full GRU (dup x8, blk&7==0 commits) + q for a-quarter (dup x2) +
// e-partials for a-quarter x l-half. blk: b=blk>>3, yq=(blk>>1)&3, lh=blk&1
static __device__ void ph_gqe(const KP& p, char* sm, int blk, int t){
  const int tid = threadIdx.x;
  const int b = blk>>3, yq = (blk>>1)&3, lh = blk&1;
  float* s_lds = (float*)sm;            // 512 f
  float* q_lds = s_lds + 512;           // 128 f
  const float* gAb = p.gA + (size_t)b*N1;
  const float* gBb = p.gB + (size_t)b*N1;
  const float* ge = p.gre + (size_t)(t*NB + b)*NW;
  const float* s_old = (t&1) ? p.sbufB : p.sbufA;
  float* s_new       = (t&1) ? p.sbufA : p.sbufB;
  u16* x1n = p.x1A + (size_t)(t+1)*NB*K1 + (size_t)b*K1;
#pragma unroll
  for (int h=0; h<2; h++){
    const int j = tid + h*256;
    float g0 = atL(gAb + j)      + atL(gBb + j);
    float g1 = atL(gAb + 512+j)  + atL(gBb + 512+j);
    float g2 = atL(gAb + 1024+j) + atL(gBb + 1024+j);
    float g3 = atL(gAb + 1536+j) + atL(gBb + 1536+j);
    float r = fsig(g0 + ge[j] + p.bih[j] + p.bhh[j]);
    float z = fsig(g1 + ge[512+j] + p.bih[512+j] + p.bhh[512+j]);
    float n = ftanh(ge[1024+j] + g3 + p.bih[1024+j] + r*(g2 + p.bhh[1024+j]));
    float sn = (1.f-z)*n + z*atL(s_old + (size_t)b*512 + j);
    s_lds[j] = sn;
    if ((blk&7)==0){
      atS(s_new + (size_t)b*512 + j, sn);
      u32 me = f2b(sn);
      u32 oth = (u32)__shfl_xor((int)me, 1);
      if (!(tid&1)) atSu((u32*)(x1n + j), me | (oth<<16));
    }
  }
  __syncthreads();
  {
    const int al = tid>>1, kh = tid&1;        // al 0..127
    const int a = yq*128 + al;
    const u16* wr = p.Wsb + (size_t)a*512 + kh*256;
    const float* sp = s_lds + kh*256;
    float acc = 0.f;
#pragma unroll 8
    for (int k=0;k<256;k+=8){
      bf16x8 w = *(const bf16x8*)(wr + k);
#pragma unroll
      for (int j=0;j<8;j++) acc += sp[k+j]*b2f((u16)w[j]);
    }
    acc += __shfl_xor(acc, 1);
    if (kh==0) q_lds[al] = acc + p.attb[a];
  }
  __syncthreads();
  const int lane = tid&63, wv = tid>>6;
  const int g16 = lane>>4, sub = lane&15;
  const int gid = wv*4 + g16;              // 16 groups of 16 lanes
  float v8[8], q8[8];
#pragma unroll
  for (int j=0;j<8;j++){
    v8[j] = p.attv[yq*128 + sub*8 + j];
    q8[j] = q_lds[sub*8 + j];
  }
  float* epo = p.e + ((size_t)yq*NB + b)*NL;
  const int i0 = lh ? 13 : 0, i1 = lh ? 25 : 13;
  for (int i=i0;i<i1;i++){
    const int l = i*16 + gid;              // lh=0: l in [0,208); lh=1: [208,400)
    const u16* ep = p.eproj + ((size_t)b*NL + l)*512 + yq*128 + sub*8;
    bf16x8 w8 = *(const bf16x8*)ep;
    float acc = 0.f;
#pragma unroll
    for (int j8=0;j8<8;j8++) acc += v8[j8]*ftanh(b2f((u16)w8[j8]) + q8[j8]);
    acc += __shfl_xor(acc,1); acc += __shfl_xor(acc,2);
    acc += __shfl_xor(acc,4); acc += __shfl_xor(acc,8);
    if (sub==0) atS(epo + l, acc);
  }
}

// P3: combine 4 e-partials + mask + softmax (dup x8) + ctx (64-j slice,
// 4 threads per j over aligned l-chunks {104,104,104,88}). blk: b=blk>>3, yo=blk&7
static __device__ void ph_smctx(const KP& p, char* sm, int blk, int t){
  const int tid = threadIdx.x;
  const int b = blk>>3, yo = blk&7;
  const int lane = tid&63, wv = tid>>6;
  float* a_lds = (float*)sm;            // 400 f
  float* red   = (float*)(sm+1600);     // 4 f
  float* bc    = (float*)(sm+1664);     // 2 f
  float s0 = atL(p.e + (size_t)b*NL + tid)
           + atL(p.e + ((size_t)NB + b)*NL + tid)
           + atL(p.e + ((size_t)2*NB + b)*NL + tid)
           + atL(p.e + ((size_t)3*NB + b)*NL + tid);
  float ev0 = (p.src[b*NL + tid]!=0) ? s0 : -INFINITY;
  float ev1 = -INFINITY;
  if (tid < NL-256){
    float s1 = atL(p.e + (size_t)b*NL + tid+256)
             + atL(p.e + ((size_t)NB + b)*NL + tid+256)
             + atL(p.e + ((size_t)2*NB + b)*NL + tid+256)
             + atL(p.e + ((size_t)3*NB + b)*NL + tid+256);
    ev1 = (p.src[b*NL + tid+256]!=0) ? s1 : -INFINITY;
  }
  float mx = fmaxf(ev0, ev1);
  for (int off=32; off; off>>=1) mx = fmaxf(mx, __shfl_xor(mx, off));
  if (lane==0) red[wv]=mx;
  __syncthreads();
  if (tid==0) bc[0] = fmaxf(fmaxf(red[0],red[1]), fmaxf(red[2],red[3]));
  __syncthreads();
  const float M = bc[0];
  float p0 = (ev0==-INFINITY)? 0.f : __expf(ev0 - M);
  float p1 = (ev1==-INFINITY)? 0.f : __expf(ev1 - M);
  float sm2 = p0 + p1;
  for (int off=32; off; off>>=1) sm2 += __shfl_xor(sm2, off);
  if (lane==0) red[wv]=sm2;
  __syncthreads();
  if (tid==0) bc[1] = red[0]+red[1]+red[2]+red[3];
  __syncthreads();
  const float inv = 1.f / bc[1];
  a_lds[tid] = p0*inv;
  if (tid < NL-256) a_lds[tid+256] = p1*inv;
  __syncthreads();
  if (yo==0){
    float* ab = p.attn_all + ((size_t)t*NB + b)*NL;
    ab[tid] = a_lds[tid];
    if (tid < NL-256) ab[tid+256] = a_lds[tid+256];
  }
  // ctx: j = yo*64 + tid/4; 4 threads per j, l-chunks {104,104,104,88}
  const int j = yo*64 + (tid>>2), lq = tid&3;
  const int l0 = lq*104;
  const int nm = (lq<3) ? 13 : 11;
  const u16* er = p.encT + ((size_t)b*512 + j)*NL + l0;
  const float* ap = a_lds + l0;
  float acc = 0.f;
  for (int m=0;m<nm;m++){
    bf16x8 e8 = *(const bf16x8*)(er + m*8);
#pragma unroll
    for (int jj=0;jj<8;jj++) acc += ap[m*8+jj]*b2f((u16)e8[jj]);
  }
  acc += __shfl_xor(acc,1); acc += __shfl_xor(acc,2);
  u32 me = f2b(acc);
  u32 oth = (u32)__shfl_xor((int)me, 4);
  if ((tid&7)==0)
    atSu((u32*)(p.x1A + (size_t)(t+1)*NB*K1 + (size_t)b*K1 + 512 + j), me | (oth<<16));
  if ((tid&3)==0) atS(p.ctx_ws + (size_t)b*512 + j, acc);
}

// pcopy for step t. u 0..3
static __device__ void ph_pcopy(const KP& p, int u, int t){
  const int tid = threadIdx.x;
  const float* sN = (t&1) ? p.sbufA : p.sbufB;
  const int b = u*32 + (tid>>3), kq = tid&7;
  const float* v = (kq<4) ? (sN + (size_t)b*512 + kq*128) : (p.ctx_ws + (size_t)b*512 + (kq-4)*128);
  const float* w = p.copyW + kq*128;
  float acc = 0.f;
#pragma unroll 8
  for (int k=0;k<128;k++) acc += atL(v+k)*w[k];
  acc += __shfl_xor(acc,1); acc += __shfl_xor(acc,2); acc += __shfl_xor(acc,4);
  if (kq==0) p.pcb_all[(size_t)t*NB + b] = fsig(acc + p.copyb[0]);
}

__global__ __launch_bounds__(256,4) void k_persist(KP p){
  __shared__ __align__(16) char sm[33024];
  const int blk = blockIdx.x;
  u32 ep = 0;
  for (int t=0; t<NT; ++t){
    if (blk < 32) ph_g1(p, sm, blk, t);
    else if (blk < 36){ if (t > 0) ph_pcopy(p, blk-32, t-1); }
    gbar(p, ep);
    ph_gqe(p, sm, blk, t);
    gbar(p, ep);
    ph_smctx(p, sm, blk, t);
    gbar(p, ep);
  }
  if (blk < 4) ph_pcopy(p, blk, NT-1);
}

// ---------------- pass-B kernels (batched over all 30 steps) ----------------

__global__ __launch_bounds__(256) void kB_read(const u16* __restrict__ x1A, const u16* __restrict__ W2,
    const float* __restrict__ gre, const float* __restrict__ readb, u16* __restrict__ mbf_all){
  __shared__ __align__(16) u16 ls[16384];
  const int t = blockIdx.y, n0 = blockIdx.x*128;
  const u16* A = x1A + (size_t)(t+1)*NB*K1;
  f32x4 acc[4][4];
  gemm_pipe(A, K1, W2 + (size_t)n0*K1, K1, K1, ls, acc);
  const int tid=threadIdx.x, wave=tid>>6, lane=tid&63, wm=wave>>1, wn=wave&1;
#pragma unroll
  for (int mi=0;mi<4;mi++)
#pragma unroll
    for (int nj=0;nj<4;nj++)
#pragma unroll
      for (int q=0;q<4;q++){
        int r = wm*64 + mi*16 + (lane>>4)*4 + q;
        int c = n0 + wn*64 + nj*16 + (lane&15);
        float v = acc[mi][nj][q] + readb[c] + gre[((size_t)(t*NB + r))*NW + 1536 + c];
        float o = __shfl_xor(v, 1);
        float mx2 = fmaxf(v, o);
        if (!(lane&1)) mbf_all[(size_t)(t*NB + r)*256 + (c>>1)] = f2b(mx2);
      }
}

__global__ __launch_bounds__(256) void kB_lse(const u16* __restrict__ mbf_all, const u16* __restrict__ WoP,
    float* __restrict__ parts){
  __shared__ __align__(16) u16 ls[16384];
  __shared__ float psum[128][2];
  const int t = blockIdx.y, n0 = blockIdx.x*128;
  f32x4 acc[4][4];
  gemm_pipe(mbf_all + (size_t)t*NB*256, 256, WoP + (size_t)n0*256, 256, 256, ls, acc);
  const int tid=threadIdx.x, wave=tid>>6, lane=tid&63, wm=wave>>1, wn=wave&1;
  float rs[4][4];
#pragma unroll
  for (int mi=0;mi<4;mi++)
#pragma unroll
    for (int q=0;q<4;q++) rs[mi][q]=0.f;
#pragma unroll
  for (int mi=0;mi<4;mi++)
#pragma unroll
    for (int nj=0;nj<4;nj++){
      const int c = n0 + wn*64 + nj*16 + (lane&15);
#pragma unroll
      for (int q=0;q<4;q++)
        if (c < NV) rs[mi][q] += __expf(acc[mi][nj][q]);
    }
#pragma unroll
  for (int mi=0;mi<4;mi++)
#pragma unroll
    for (int q=0;q<4;q++){
      float v = rs[mi][q];
      v += __shfl_xor(v,1); v += __shfl_xor(v,2); v += __shfl_xor(v,4); v += __shfl_xor(v,8);
      if ((lane&15)==0) psum[wm*64 + mi*16 + (lane>>4)*4 + q][wn] = v;
    }
  __syncthreads();
  if (tid < 128) parts[(size_t)(t*NB + tid)*160 + blockIdx.x] = psum[tid][0] + psum[tid][1];
}

__global__ __launch_bounds__(256) void kB_lsered(const float* __restrict__ parts, float* __restrict__ LSE_all){
  const int row = blockIdx.x, tid = threadIdx.x;
  const int lane = tid&63, wv = tid>>6;
  __shared__ float red[4];
  float v = (tid<157)? parts[(size_t)row*160 + tid] : 0.f;
  for (int off=32; off; off>>=1) v += __shfl_xor(v, off);
  if (lane==0) red[wv]=v;
  __syncthreads();
  if (tid==0) LSE_all[row] = __logf(red[0]+red[1]+red[2]+red[3]);
}

__global__ __launch_bounds__(256) void kB_out2(const u16* __restrict__ mbf_all, const u16* __restrict__ WoP,
    const float* __restrict__ LSE_all, const float* __restrict__ pcb_all, float* __restrict__ out){
  __shared__ __align__(16) u16 ls[16384];
  const int t = blockIdx.y, n0 = blockIdx.x*128;
  f32x4 acc[4][4];
  gemm_pipe(mbf_all + (size_t)t*NB*256, 256, WoP + (size_t)n0*256, 256, 256, ls, acc);
  const int tid=threadIdx.x, wave=tid>>6, lane=tid&63, wm=wave>>1, wn=wave&1;
  float lse_r[4][4], lo_r[4][4];
#pragma unroll
  for (int mi=0;mi<4;mi++)
#pragma unroll
    for (int q=0;q<4;q++){
      const int r = wm*64 + mi*16 + (lane>>4)*4 + q;
      lse_r[mi][q] = LSE_all[(size_t)t*NB + r];
      lo_r[mi][q]  = 1.f - pcb_all[(size_t)t*NB + r];
    }
#pragma unroll
  for (int mi=0;mi<4;mi++)
#pragma unroll
    for (int nj=0;nj<4;nj++){
      const int c = n0 + wn*64 + nj*16 + (lane&15);
      if (c >= NV) continue;
#pragma unroll
      for (int q=0;q<4;q++){
        const int r = wm*64 + mi*16 + (lane>>4)*4 + q;
        out[((size_t)r*NT + t)*OUTW + c] = __logf(lo_r[mi][q]*__expf(acc[mi][nj][q]-lse_r[mi][q]) + 1e-12f);
      }
    }
}

__global__ __launch_bounds__(256) void kB_copy(const float* __restrict__ pcb_all, const float* __restrict__ attn_all,
    float* __restrict__ out){
  const int total = NT*NB*NL;
  for (int idx = blockIdx.x*256 + threadIdx.x; idx < total; idx += gridDim.x*256){
    int t = idx / (NB*NL);
    int rem = idx - t*(NB*NL);
    int b = rem / NL, l = rem - b*NL;
    float pc = pcb_all[(size_t)t*NB + b];
    float av = attn_all[((size_t)t*NB + b)*NL + l];
    out[((size_t)b*NT + t)*OUTW + NV + l] = __logf(pc*av + 1e-12f);
  }
}

// ---------------- launch ----------------

extern "C" void kernel_launch(void* const* d_in, const int* in_sizes, int n_in,
                              void* d_out, int out_size, void* d_ws, size_t ws_size,
                              hipStream_t stream){
  const float* enc   = (const float*)d_in[0];
  const float* s_in  = (const float*)d_in[1];
  const int*   src   = (const int*)d_in[2];
  const int*   tgt   = (const int*)d_in[3];
  const float* embed = (const float*)d_in[4];
  const float* W_ih  = (const float*)d_in[5];
  const float* b_ih  = (const float*)d_in[6];
  const float* W_hh  = (const float*)d_in[7];
  const float* b_hh  = (const float*)d_in[8];
  const float* attWh = (const float*)d_in[9];
  const float* attWs = (const float*)d_in[10];
  const float* attb  = (const float*)d_in[11];
  const float* attv  = (const float*)d_in[12];
  const float* copyW = (const float*)d_in[13];
  const float* copyb = (const float*)d_in[14];
  const float* readW = (const float*)d_in[15];
  const float* readb = (const float*)d_in[16];
  const float* readWo= (const float*)d_in[17];
  float* out = (float*)d_out;
  (void)in_sizes; (void)n_in; (void)out_size; (void)ws_size;

  char* wsp = (char*)d_ws;
  size_t off = 0;
  auto alloc = [&](size_t bytes)->char*{ char* p = wsp + off; off = (off + bytes + 255) & ~(size_t)255; return p; };
  u16* enc_bf    = (u16*)alloc((size_t)NB*NL*NHE*2);
  u16* encT      = (u16*)alloc((size_t)NB*NHE*NL*2);
  u16* eproj     = (u16*)alloc((size_t)NB*NL*NA*2);
  u16* attWh_bf  = (u16*)alloc((size_t)NA*NHE*2);
  u16* Wsb       = (u16*)alloc((size_t)NA*NHD*2);
  u16* W1        = (u16*)alloc((size_t)N1*K1*2);
  u16* W2        = (u16*)alloc((size_t)512*K1*2);
  u16* Wemb      = (u16*)alloc((size_t)NW*KE*2);
  u16* Xemb      = (u16*)alloc((size_t)NT*NB*KE*2);
  u16* WoP       = (u16*)alloc((size_t)NVP*256*2);
  float* gre     = (float*)alloc((size_t)NT*NB*NW*4);
  float* gA      = (float*)alloc((size_t)NB*N1*4);
  float* gB      = (float*)alloc((size_t)NB*N1*4);
  u16* x1A       = (u16*)alloc((size_t)(NT+1)*NB*K1*2);
  float* sbufA   = (float*)alloc((size_t)NB*NHD*4);
  float* sbufB   = (float*)alloc((size_t)NB*NHD*4);
  float* e_buf   = (float*)alloc((size_t)4*NB*NL*4);
  float* attn_all= (float*)alloc((size_t)NT*NB*NL*4);
  float* ctx_ws  = (float*)alloc((size_t)NB*NHE*4);
  u16* mbf_all   = (u16*)alloc((size_t)NT*NB*256*2);
  float* parts   = (float*)alloc((size_t)NT*NB*160*4);
  float* LSE_all = (float*)alloc((size_t)NT*NB*4);
  float* pcb_all = (float*)alloc((size_t)NT*NB*4);
  u32* slots     = (u32*)alloc((size_t)NBLK*4);
  u32* gen       = (u32*)alloc((size_t)64*64);

  hipMemsetAsync(slots, 0, (size_t)NBLK*4, stream);
  hipMemsetAsync(gen,   0, (size_t)64*64, stream);

  k_conv_flat<<<4096,256,0,stream>>>(enc, enc_bf, (long)NB*NL*NHE);
  k_transpose<<<dim3(16,128),512,0,stream>>>(enc, encT);
  k_conv_flat<<<1024,256,0,stream>>>(attWh, attWh_bf, (long)NA*NHE);
  k_conv_flat<<<1024,256,0,stream>>>(attWs, Wsb, (long)NA*NHD);
  k_build_w1<<<8192,256,0,stream>>>(W_hh, W_ih, W1);
  k_build_w2<<<2048,256,0,stream>>>(readW, W2);
  k_build_wemb<<<2560,256,0,stream>>>(W_ih, readW, Wemb);
  k_build_xemb<<<4800,256,0,stream>>>(tgt, embed, Xemb);
  k_convpad<<<2048,256,0,stream>>>(readWo, WoP, NV, 256, 256, (long)NVP*256);
  k_init<<<512,256,0,stream>>>(s_in, sbufA, x1A);
  k_encproj<<<dim3(4,400),256,0,stream>>>(enc_bf, attWh_bf, eproj);
  k_gemm_emb<<<dim3(16,30),256,0,stream>>>(Xemb, Wemb, gre);

  KP kp;
  kp.bih = b_ih; kp.bhh = b_hh; kp.attb = attb; kp.attv = attv;
  kp.copyW = copyW; kp.copyb = copyb;
  kp.src = src;
  kp.Wsb = Wsb; kp.eproj = eproj; kp.encT = encT; kp.W1 = W1;
  kp.gre = gre;
  kp.gA = gA; kp.gB = gB; kp.sbufA = sbufA; kp.sbufB = sbufB;
  kp.e = e_buf; kp.ctx_ws = ctx_ws; kp.attn_all = attn_all; kp.pcb_all = pcb_all;
  kp.x1A = x1A;
  kp.slots = slots; kp.gen = gen;

  k_persist<<<NBLK,256,0,stream>>>(kp);

  kB_read<<<dim3(4,NT),256,0,stream>>>(x1A, W2, gre, readb, mbf_all);
  kB_lse<<<dim3(157,NT),256,0,stream>>>(mbf_all, WoP, parts);
  kB_lsered<<<NT*NB,256,0,stream>>>(parts, LSE_all);
  kB_out2<<<dim3(157,NT),256,0,stream>>>(mbf_all, WoP, LSE_all, pcb_all, out);
  kB_copy<<<1024,256,0,stream>>>(pcb_all, attn_all, out);
}

// Round 12
// 2850.395 us; speedup vs baseline: 1.5010x; 1.5010x over previous
//
#include <hip/hip_runtime.h>

typedef unsigned char u8;
typedef unsigned short u16;
typedef unsigned int u32;
typedef short bf16x8 __attribute__((ext_vector_type(8)));
typedef float f32x4 __attribute__((ext_vector_type(4)));

#define NB 128
#define NL 400
#define NT 30
#define NE 300
#define KE 320
#define NHE 512
#define NHD 512
#define NA 512
#define NV 20000
#define NVP 20096
#define K1 1024
#define N1 2048
#define NW 2048
#define OUTW (NV+NL)
#define NBLK 512

static __device__ __forceinline__ u16 f2b(float x){ u32 u=__float_as_uint(x); u += 0x7FFFu + ((u>>16)&1u); return (u16)(u>>16); }
static __device__ __forceinline__ float b2f(u16 h){ return __uint_as_float(((u32)h)<<16); }
static __device__ __forceinline__ float fsig(float x){ return 1.f/(1.f+__expf(-x)); }
static __device__ __forceinline__ float ftanh(float x){ return 1.f - 2.f/(__expf(2.f*x)+1.f); }

// f32 -> fp8 e4m3 (RNE; inputs well inside range; fp8-subnormals -> 0-ish ok)
static __device__ __forceinline__ u8 f2e4(float x){
  u32 u = __float_as_uint(x);
  u32 s = (u>>24) & 0x80u;
  u32 m = __float_as_uint(__uint_as_float(u & 0x7FFFFFFFu) * 0x1p-120f);
  m += 0x7FFFFu + ((m>>20)&1u);
  return (u8)(s | ((m>>20) & 0x7Fu));
}
// fp8 e4m3 -> f32 (exact, incl. subnormals)
static __device__ __forceinline__ float e42f(u32 b){
  u32 f = ((b & 0x80u) << 24) | ((b & 0x7Fu) << 20);
  return __uint_as_float(f) * 0x1p120f;
}

static __device__ __forceinline__ float atL(const float* p){ return __hip_atomic_load(p, __ATOMIC_RELAXED, __HIP_MEMORY_SCOPE_AGENT); }
static __device__ __forceinline__ u32   atLu(const u32* p){ return __hip_atomic_load(p, __ATOMIC_RELAXED, __HIP_MEMORY_SCOPE_AGENT); }
static __device__ __forceinline__ void  atS(float* p, float v){ __hip_atomic_store(p, v, __ATOMIC_RELAXED, __HIP_MEMORY_SCOPE_AGENT); }
static __device__ __forceinline__ void  atSu(u32* p, u32 v){ __hip_atomic_store(p, v, __ATOMIC_RELAXED, __HIP_MEMORY_SCOPE_AGENT); }

static __device__ __forceinline__ void gll16(const u16* g, u16* l){
  __builtin_amdgcn_global_load_lds((const __attribute__((address_space(1))) void*)g,
                                   (__attribute__((address_space(3))) void*)l, 16, 0, 0);
}

// Pipelined 128x128 tile GEMM: A[M,K] x B[N,K] row-major bf16, f32 accum. 256 thr.
static __device__ __forceinline__ void gemm_pipe(const u16* A, int lda, const u16* Bm, int ldb,
                                                 int K, u16* ls, f32x4 (&acc)[4][4]){
  const int tid = threadIdx.x;
  const int wave = tid>>6, lane = tid&63;
  const int srow = lane>>2;
  const int sko = (((lane&3) ^ ((lane>>3)&3)))*8;
  const int wm = wave>>1, wn = wave&1;
#pragma unroll
  for (int i=0;i<4;i++)
#pragma unroll
    for (int j=0;j<4;j++)
#pragma unroll
      for (int q=0;q<4;q++) acc[i][j][q] = 0.f;
  const int nk = K>>5;
  auto issue = [&](int kt, int bsel){
    u16* dA = ls + bsel*8192;
    u16* dB = dA + 4096;
#pragma unroll
    for (int i=0;i<2;i++){
      const int c = wave*2+i;
      const int row = c*16 + srow;
      gll16(A + (size_t)row*lda + kt + sko, dA + c*512);
      gll16(Bm + (size_t)row*ldb + kt + sko, dB + c*512);
    }
  };
  issue(0, 0);
  issue(nk>1 ? 32 : 0, 1);
  for (int it=0; it<nk; ++it){
    asm volatile("s_waitcnt vmcnt(4)" ::: "memory");
    __builtin_amdgcn_s_barrier();
    const u16* lsA = ls + (it&1)*8192;
    const u16* lsB = lsA + 4096;
    const int rsel = (lane&15)*32 + (((lane>>4) ^ ((lane>>1)&3))*8);
    bf16x8 aF[4], bF[4];
#pragma unroll
    for (int mi=0;mi<4;mi++) aF[mi] = *(const bf16x8*)(lsA + (wm*64+mi*16)*32 + rsel);
#pragma unroll
    for (int nj=0;nj<4;nj++) bF[nj] = *(const bf16x8*)(lsB + (wn*64+nj*16)*32 + rsel);
#pragma unroll
    for (int mi=0;mi<4;mi++)
#pragma unroll
      for (int nj=0;nj<4;nj++)
        acc[mi][nj] = __builtin_amdgcn_mfma_f32_16x16x32_bf16(aF[mi], bF[nj], acc[mi][nj], 0,0,0);
    __builtin_amdgcn_s_barrier();
    issue(it+2 < nk ? (it+2)*32 : 0, it&1);
  }
  asm volatile("s_waitcnt vmcnt(0)" ::: "memory");
  __builtin_amdgcn_s_barrier();
}

// ---------------- setup kernels ----------------

__global__ __launch_bounds__(256) void k_conv_flat(const float* __restrict__ s, u16* __restrict__ d, long n){
  long i = (long)blockIdx.x*256 + threadIdx.x;
  const long st = (long)gridDim.x*256;
  for (; i<n; i+=st) d[i] = f2b(s[i]);
}

__global__ __launch_bounds__(256) void k_conv_fp8(const float* __restrict__ s, u8* __restrict__ d, long n){
  long i = (long)blockIdx.x*256 + threadIdx.x;
  const long st = (long)gridDim.x*256;
  for (; i<n; i+=st) d[i] = f2e4(s[i]);
}

__global__ __launch_bounds__(256) void k_convpad(const float* __restrict__ s, u16* __restrict__ d,
                                                 int srows, int sk, int dk, long total){
  long i = (long)blockIdx.x*256 + threadIdx.x;
  const long st = (long)gridDim.x*256;
  for (; i<total; i+=st){
    int r = (int)(i / dk), k = (int)(i - (long)r*dk);
    d[i] = (r < srows && k < sk) ? f2b(s[(size_t)r*sk + k]) : (u16)0;
  }
}

// encT8[b][j][l] fp8 from enc[b][l][j] f32. grid (16, 128), 512 thr
__global__ __launch_bounds__(512) void k_transpose(const float* __restrict__ enc, u8* __restrict__ encT8){
  const int b = blockIdx.y, jt = blockIdx.x;
  __shared__ float tile[16][33];
  const int tid = threadIdx.x;
  for (int lt=0; lt<25; lt++){
    {
      int l = lt*16 + (tid>>5), j = jt*32 + (tid&31);
      tile[tid>>5][tid&31] = enc[((size_t)b*NL + l)*512 + j];
    }
    __syncthreads();
    {
      int jw = tid>>4, lw = tid&15;
      encT8[((size_t)b*512 + jt*32 + jw)*NL + lt*16 + lw] = f2e4(tile[lw][jw]);
    }
    __syncthreads();
  }
}

// W1[2048][1024]: rows 0..1024 [Whh_rz|Wih_ctx_rz]; 1024..1536 [Whh_n|0]; 1536..2048 [0|Wih_ctx_n]
__global__ __launch_bounds__(256) void k_build_w1(const float* __restrict__ Whh, const float* __restrict__ Wih, u16* __restrict__ d){
  int idx = blockIdx.x*256 + threadIdx.x;
  if (idx >= N1*K1) return;
  int n = idx >> 10, k = idx & 1023;
  float v = 0.f;
  if (n < 1024)       v = (k<512) ? Whh[(size_t)n*512 + k] : Wih[(size_t)n*812 + 300 + (k-512)];
  else if (n < 1536)  v = (k<512) ? Whh[(size_t)n*512 + k] : 0.f;
  else                v = (k<512) ? 0.f : Wih[(size_t)(n-512)*812 + 300 + (k-512)];
  d[idx] = f2b(v);
}

__global__ __launch_bounds__(256) void k_build_w2(const float* __restrict__ Wr, u16* __restrict__ d){
  int idx = blockIdx.x*256 + threadIdx.x;
  if (idx >= 512*K1) return;
  int r = idx >> 10, k = idx & 1023;
  float v = (k<512) ? Wr[(size_t)r*1324 + 812 + k] : Wr[(size_t)r*1324 + 300 + (k-512)];
  d[idx] = f2b(v);
}

__global__ __launch_bounds__(256) void k_build_wemb(const float* __restrict__ Wih, const float* __restrict__ Wr, u16* __restrict__ d){
  int idx = blockIdx.x*256 + threadIdx.x;
  if (idx >= NW*KE) return;
  int n = idx / KE, k = idx - n*KE;
  float v = 0.f;
  if (k < NE) v = (n < 1536) ? Wih[(size_t)n*812 + k] : Wr[(size_t)(n-1536)*1324 + k];
  d[idx] = f2b(v);
}

__global__ __launch_bounds__(256) void k_build_xemb(const int* __restrict__ tgt, const float* __restrict__ embed, u16* __restrict__ d){
  int idx = blockIdx.x*256 + threadIdx.x;
  if (idx >= NT*NB*KE) return;
  int row = idx / KE, k = idx - row*KE;
  int t = row >> 7, b = row & 127;
  u16 hv = 0;
  if (k < NE){
    int w = 2;
    if (t > 0){ w = tgt[b*NT + t-1]; if ((u32)w >= (u32)NV) w = 1; }
    hv = f2b(embed[(size_t)w*NE + k]);
  }
  d[idx] = hv;
}

__global__ __launch_bounds__(256) void k_init(const float* __restrict__ s_in, float* __restrict__ sbuf0, u16* __restrict__ x1A){
  int idx = blockIdx.x*256 + threadIdx.x;
  if (idx < 65536){
    int b = idx>>9, j = idx&511;
    float v = s_in[idx];
    sbuf0[idx] = v;
    x1A[(size_t)b*K1 + j] = f2b(v);
  } else if (idx < 131072){
    int k = idx - 65536;
    int b = k>>9, j = k&511;
    x1A[(size_t)b*K1 + 512 + j] = 0;
  }
}

// eproj8 = fp8(enc @ att_Wh^T). grid (4,400)
__global__ __launch_bounds__(256) void k_encproj(const u16* __restrict__ A, const u16* __restrict__ Bw, u8* __restrict__ C8){
  __shared__ __align__(16) u16 ls[16384];
  const int n0 = blockIdx.x*128, m0 = blockIdx.y*128;
  f32x4 acc[4][4];
  gemm_pipe(A + (size_t)m0*512, 512, Bw + (size_t)n0*512, 512, 512, ls, acc);
  const int tid=threadIdx.x, wave=tid>>6, lane=tid&63, wm=wave>>1, wn=wave&1;
#pragma unroll
  for (int mi=0;mi<4;mi++)
#pragma unroll
    for (int nj=0;nj<4;nj++)
#pragma unroll
      for (int q=0;q<4;q++){
        int r = m0 + wm*64 + mi*16 + (lane>>4)*4 + q;
        int c = n0 + wn*64 + nj*16 + (lane&15);
        C8[(size_t)r*512 + c] = f2e4(acc[mi][nj][q]);
      }
}

__global__ __launch_bounds__(256) void k_gemm_emb(const u16* __restrict__ Xe, const u16* __restrict__ We, float* __restrict__ gre){
  __shared__ __align__(16) u16 ls[16384];
  const int n0 = blockIdx.x*128, m0 = blockIdx.y*128;
  f32x4 acc[4][4];
  gemm_pipe(Xe + (size_t)m0*KE, KE, We + (size_t)n0*KE, KE, KE, ls, acc);
  const int tid=threadIdx.x, wave=tid>>6, lane=tid&63, wm=wave>>1, wn=wave&1;
#pragma unroll
  for (int mi=0;mi<4;mi++)
#pragma unroll
    for (int nj=0;nj<4;nj++)
#pragma unroll
      for (int q=0;q<4;q++){
        int r = m0 + wm*64 + mi*16 + (lane>>4)*4 + q;
        int c = n0 + wn*64 + nj*16 + (lane&15);
        gre[(size_t)r*NW + c] = acc[mi][nj][q];
      }
}

// ---------------- persistent pass-A kernel (recurrence only) ----------------

struct KP {
  const float *bih, *bhh, *attb, *attv, *copyW, *copyb;
  const int   *src;
  const u8    *Wsb8, *eproj8, *encT8;
  const u16   *W1;
  const float *gre;
  float *gA, *gB, *sbufA, *sbufB, *e, *ctx_ws, *attn_all, *pcb_all;
  u16   *x1A;
  u32   *slots, *gen;
};

// Fence-free flag-array barrier, distributed gen lines (8 pollers/line).
static __device__ __forceinline__ void gbar(const KP& p, u32& ep){
  ++ep;
  asm volatile("s_waitcnt vmcnt(0)" ::: "memory");
  __syncthreads();
  if (threadIdx.x==0)
    atSu(p.slots + blockIdx.x, ep);
  if (blockIdx.x==0){
    if (threadIdx.x < 64){
      const u32* sl = p.slots + threadIdx.x*8;
      for (;;){
        u32 mn = 0xFFFFFFFFu;
#pragma unroll
        for (int j=0;j<8;j++){
          u32 v = atLu(sl+j);
          mn = v<mn ? v : mn;
        }
        if (__all(mn >= ep)) break;
        __builtin_amdgcn_s_sleep(4);
      }
      atSu(p.gen + threadIdx.x*16, ep);
    }
  } else if (threadIdx.x==0){
    const u32* gp = p.gen + (blockIdx.x>>3)*16;
    while (atLu(gp) < ep) __builtin_amdgcn_s_sleep(4);
  }
  asm volatile("" ::: "memory");
  __syncthreads();
}

// P1: g = x1A[t] @ W1^T, 2-way K-split. u 0..31: ks=u&1, ntile=u>>1
static __device__ void ph_g1(const KP& p, char* sm, int u, int t){
  u16* ls = (u16*)sm;
  const int ks = u&1, n0 = (u>>1)*128;
  const u16* A  = p.x1A + (size_t)t*NB*K1 + ks*512;
  const u16* Bm = p.W1 + (size_t)n0*K1 + ks*512;
  f32x4 acc[4][4];
  gemm_pipe(A, K1, Bm, K1, 512, ls, acc);
  float* gd = ks ? p.gB : p.gA;
  const int tid=threadIdx.x, wave=tid>>6, lane=tid&63, wm=wave>>1, wn=wave&1;
#pragma unroll
  for (int mi=0;mi<4;mi++)
#pragma unroll
    for (int nj=0;nj<4;nj++)
#pragma unroll
      for (int q=0;q<4;q++){
        int r = wm*64 + mi*16 + (lane>>4)*4 + q;
        int c = n0 + wn*64 + nj*16 + (lane&15);
        atS(gd + (size_t)r*N1 + c, acc[mi][nj][q]);
      }
}

// P2: full GRU (dup x4, yq==0 commits) + q for a-quarter (fp8 Wsb) +
// e-partials for a-quarter (fp8 eproj). blk: b=blk>>2, yq=blk&3
static __device__ void ph_gqe(const KP& p, char* sm, int blk, int t){
  const int tid = threadIdx.x;
  const int b = blk>>2, yq = blk&3;
  float* s_lds = (float*)sm;            // 512 f
  float* q_lds = s_lds + 512;           // 128 f
  const float* gAb = p.gA + (size_t)b*N1;
  const float* gBb = p.gB + (size_t)b*N1;
  const float* ge = p.gre + (size_t)(t*NB + b)*NW;
  const float* s_old = (t&1) ? p.sbufB : p.sbufA;
  float* s_new       = (t&1) ? p.sbufA : p.sbufB;
  u16* x1n = p.x1A + (size_t)(t+1)*NB*K1 + (size_t)b*K1;
#pragma unroll
  for (int h=0; h<2; h++){
    const int j = tid + h*256;
    float g0 = atL(gAb + j)      + atL(gBb + j);
    float g1 = atL(gAb + 512+j)  + atL(gBb + 512+j);
    float g2 = atL(gAb + 1024+j) + atL(gBb + 1024+j);
    float g3 = atL(gAb + 1536+j) + atL(gBb + 1536+j);
    float r = fsig(g0 + ge[j] + p.bih[j] + p.bhh[j]);
    float z = fsig(g1 + ge[512+j] + p.bih[512+j] + p.bhh[512+j]);
    float n = ftanh(ge[1024+j] + g3 + p.bih[1024+j] + r*(g2 + p.bhh[1024+j]));
    float sn = (1.f-z)*n + z*atL(s_old + (size_t)b*512 + j);
    s_lds[j] = sn;
    if (yq==0){
      atS(s_new + (size_t)b*512 + j, sn);
      u32 me = f2b(sn);
      u32 oth = (u32)__shfl_xor((int)me, 1);
      if (!(tid&1)) atSu((u32*)(x1n + j), me | (oth<<16));
    }
  }
  __syncthreads();
  {
    const int al = tid>>1, kh = tid&1;        // al 0..127
    const int a = yq*128 + al;
    const u8* wr = p.Wsb8 + (size_t)a*512 + kh*256;
    const float* sp = s_lds + kh*256;
    float acc = 0.f;
#pragma unroll 8
    for (int k=0;k<256;k+=8){
      const uint2 w = *(const uint2*)(wr + k);
#pragma unroll
      for (int j=0;j<4;j++) acc += sp[k+j]*e42f((w.x>>(8*j))&0xFFu);
#pragma unroll
      for (int j=0;j<4;j++) acc += sp[k+4+j]*e42f((w.y>>(8*j))&0xFFu);
    }
    acc += __shfl_xor(acc, 1);
    if (kh==0) q_lds[al] = acc + p.attb[a];
  }
  __syncthreads();
  const int lane = tid&63, wv = tid>>6;
  const int g16 = lane>>4, sub = lane&15;
  const int gid = wv*4 + g16;              // 16 groups of 16 lanes
  float v8[8], q8[8];
#pragma unroll
  for (int j=0;j<8;j++){
    v8[j] = p.attv[yq*128 + sub*8 + j];
    q8[j] = q_lds[sub*8 + j];
  }
  float* epo = p.e + ((size_t)yq*NB + b)*NL;
#pragma unroll 5
  for (int i=0;i<25;i++){
    const int l = i*16 + gid;              // covers all 400 l's
    const u8* ep = p.eproj8 + ((size_t)b*NL + l)*512 + yq*128 + sub*8;
    const uint2 w = *(const uint2*)ep;
    float acc = 0.f;
#pragma unroll
    for (int j8=0;j8<4;j8++) acc += v8[j8]*ftanh(e42f((w.x>>(8*j8))&0xFFu) + q8[j8]);
#pragma unroll
    for (int j8=0;j8<4;j8++) acc += v8[4+j8]*ftanh(e42f((w.y>>(8*j8))&0xFFu) + q8[4+j8]);
    acc += __shfl_xor(acc,1); acc += __shfl_xor(acc,2);
    acc += __shfl_xor(acc,4); acc += __shfl_xor(acc,8);
    if (sub==0) atS(epo + l, acc);
  }
}

// P3: combine 4 e-partials + mask + softmax (dup x4) + ctx (fp8 encT, j-quarter).
// blk: b=blk>>2, jq=blk&3
static __device__ void ph_smctx(const KP& p, char* sm, int blk, int t){
  const int tid = threadIdx.x;
  const int b = blk>>2, jq = blk&3;
  const int lane = tid&63, wv = tid>>6;
  float* a_lds = (float*)sm;            // 400 f
  float* red   = (float*)(sm+1600);     // 4 f
  float* bc    = (float*)(sm+1664);     // 2 f
  float s0 = atL(p.e + (size_t)b*NL + tid)
           + atL(p.e + ((size_t)NB + b)*NL + tid)
           + atL(p.e + ((size_t)2*NB + b)*NL + tid)
           + atL(p.e + ((size_t)3*NB + b)*NL + tid);
  float ev0 = (p.src[b*NL + tid]!=0) ? s0 : -INFINITY;
  float ev1 = -INFINITY;
  if (tid < NL-256){
    float s1 = atL(p.e + (size_t)b*NL + tid+256)
             + atL(p.e + ((size_t)NB + b)*NL + tid+256)
             + atL(p.e + ((size_t)2*NB + b)*NL + tid+256)
             + atL(p.e + ((size_t)3*NB + b)*NL + tid+256);
    ev1 = (p.src[b*NL + tid+256]!=0) ? s1 : -INFINITY;
  }
  float mx = fmaxf(ev0, ev1);
  for (int off=32; off; off>>=1) mx = fmaxf(mx, __shfl_xor(mx, off));
  if (lane==0) red[wv]=mx;
  __syncthreads();
  if (tid==0) bc[0] = fmaxf(fmaxf(red[0],red[1]), fmaxf(red[2],red[3]));
  __syncthreads();
  const float M = bc[0];
  float p0 = (ev0==-INFINITY)? 0.f : __expf(ev0 - M);
  float p1 = (ev1==-INFINITY)? 0.f : __expf(ev1 - M);
  float sm2 = p0 + p1;
  for (int off=32; off; off>>=1) sm2 += __shfl_xor(sm2, off);
  if (lane==0) red[wv]=sm2;
  __syncthreads();
  if (tid==0) bc[1] = red[0]+red[1]+red[2]+red[3];
  __syncthreads();
  const float inv = 1.f / bc[1];
  a_lds[tid] = p0*inv;
  if (tid < NL-256) a_lds[tid+256] = p1*inv;
  __syncthreads();
  if (jq==0){
    float* ab = p.attn_all + ((size_t)t*NB + b)*NL;
    ab[tid] = a_lds[tid];
    if (tid < NL-256) ab[tid+256] = a_lds[tid+256];
  }
  const int j = jq*128 + (tid>>1), lh = tid&1;
  const u8* er = p.encT8 + ((size_t)b*512 + j)*NL + lh*200;
  const float* ap = a_lds + lh*200;
  float acc = 0.f;
#pragma unroll 5
  for (int m=0;m<25;m++){
    const uint2 w = *(const uint2*)(er + m*8);
#pragma unroll
    for (int jj=0;jj<4;jj++) acc += ap[m*8+jj]*e42f((w.x>>(8*jj))&0xFFu);
#pragma unroll
    for (int jj=0;jj<4;jj++) acc += ap[m*8+4+jj]*e42f((w.y>>(8*jj))&0xFFu);
  }
  acc += __shfl_xor(acc, 1);
  u32 me = f2b(acc);
  u32 oth = (u32)__shfl_xor((int)me, 2);
  if ((tid&3)==0)
    atSu((u32*)(p.x1A + (size_t)(t+1)*NB*K1 + (size_t)b*K1 + 512 + j), me | (oth<<16));
  if (!(tid&1)) atS(p.ctx_ws + (size_t)b*512 + j, acc);
}

// pcopy for step t. u 0..3
static __device__ void ph_pcopy(const KP& p, int u, int t){
  const int tid = threadIdx.x;
  const float* sN = (t&1) ? p.sbufA : p.sbufB;
  const int b = u*32 + (tid>>3), kq = tid&7;
  const float* v = (kq<4) ? (sN + (size_t)b*512 + kq*128) : (p.ctx_ws + (size_t)b*512 + (kq-4)*128);
  const float* w = p.copyW + kq*128;
  float acc = 0.f;
#pragma unroll 8
  for (int k=0;k<128;k++) acc += atL(v+k)*w[k];
  acc += __shfl_xor(acc,1); acc += __shfl_xor(acc,2); acc += __shfl_xor(acc,4);
  if (kq==0) p.pcb_all[(size_t)t*NB + b] = fsig(acc + p.copyb[0]);
}

__global__ __launch_bounds__(256,2) void k_persist(KP p){
  __shared__ __align__(16) char sm[33024];
  const int blk = blockIdx.x;
  u32 ep = 0;
  for (int t=0; t<NT; ++t){
    if (blk < 32) ph_g1(p, sm, blk, t);
    else if (blk < 36){ if (t > 0) ph_pcopy(p, blk-32, t-1); }
    gbar(p, ep);
    ph_gqe(p, sm, blk, t);
    gbar(p, ep);
    ph_smctx(p, sm, blk, t);
    gbar(p, ep);
  }
  if (blk < 4) ph_pcopy(p, blk, NT-1);
}

// ---------------- pass-B kernels (batched over all 30 steps) ----------------

__global__ __launch_bounds__(256) void kB_read(const u16* __restrict__ x1A, const u16* __restrict__ W2,
    const float* __restrict__ gre, const float* __restrict__ readb, u16* __restrict__ mbf_all){
  __shared__ __align__(16) u16 ls[16384];
  const int t = blockIdx.y, n0 = blockIdx.x*128;
  const u16* A = x1A + (size_t)(t+1)*NB*K1;
  f32x4 acc[4][4];
  gemm_pipe(A, K1, W2 + (size_t)n0*K1, K1, K1, ls, acc);
  const int tid=threadIdx.x, wave=tid>>6, lane=tid&63, wm=wave>>1, wn=wave&1;
#pragma unroll
  for (int mi=0;mi<4;mi++)
#pragma unroll
    for (int nj=0;nj<4;nj++)
#pragma unroll
      for (int q=0;q<4;q++){
        int r = wm*64 + mi*16 + (lane>>4)*4 + q;
        int c = n0 + wn*64 + nj*16 + (lane&15);
        float v = acc[mi][nj][q] + readb[c] + gre[((size_t)(t*NB + r))*NW + 1536 + c];
        float o = __shfl_xor(v, 1);
        float mx2 = fmaxf(v, o);
        if (!(lane&1)) mbf_all[(size_t)(t*NB + r)*256 + (c>>1)] = f2b(mx2);
      }
}

__global__ __launch_bounds__(256) void kB_lse(const u16* __restrict__ mbf_all, const u16* __restrict__ WoP,
    float* __restrict__ parts){
  __shared__ __align__(16) u16 ls[16384];
  __shared__ float psum[128][2];
  const int t = blockIdx.y, n0 = blockIdx.x*128;
  f32x4 acc[4][4];
  gemm_pipe(mbf_all + (size_t)t*NB*256, 256, WoP + (size_t)n0*256, 256, 256, ls, acc);
  const int tid=threadIdx.x, wave=tid>>6, lane=tid&63, wm=wave>>1, wn=wave&1;
  float rs[4][4];
#pragma unroll
  for (int mi=0;mi<4;mi++)
#pragma unroll
    for (int q=0;q<4;q++) rs[mi][q]=0.f;
#pragma unroll
  for (int mi=0;mi<4;mi++)
#pragma unroll
    for (int nj=0;nj<4;nj++){
      const int c = n0 + wn*64 + nj*16 + (lane&15);
#pragma unroll
      for (int q=0;q<4;q++)
        if (c < NV) rs[mi][q] += __expf(acc[mi][nj][q]);
    }
#pragma unroll
  for (int mi=0;mi<4;mi++)
#pragma unroll
    for (int q=0;q<4;q++){
      float v = rs[mi][q];
      v += __shfl_xor(v,1); v += __shfl_xor(v,2); v += __shfl_xor(v,4); v += __shfl_xor(v,8);
      if ((lane&15)==0) psum[wm*64 + mi*16 + (lane>>4)*4 + q][wn] = v;
    }
  __syncthreads();
  if (tid < 128) parts[(size_t)(t*NB + tid)*160 + blockIdx.x] = psum[tid][0] + psum[tid][1];
}

__global__ __launch_bounds__(256) void kB_lsered(const float* __restrict__ parts, float* __restrict__ LSE_all){
  const int row = blockIdx.x, tid = threadIdx.x;
  const int lane = tid&63, wv = tid>>6;
  __shared__ float red[4];
  float v = (tid<157)? parts[(size_t)row*160 + tid] : 0.f;
  for (int off=32; off; off>>=1) v += __shfl_xor(v, off);
  if (lane==0) red[wv]=v;
  __syncthreads();
  if (tid==0) LSE_all[row] = __logf(red[0]+red[1]+red[2]+red[3]);
}

__global__ __launch_bounds__(256) void kB_out2(const u16* __restrict__ mbf_all, const u16* __restrict__ WoP,
    const float* __restrict__ LSE_all, const float* __restrict__ pcb_all, float* __restrict__ out){
  __shared__ __align__(16) u16 ls[16384];
  const int t = blockIdx.y, n0 = blockIdx.x*128;
  f32x4 acc[4][4];
  gemm_pipe(mbf_all + (size_t)t*NB*256, 256, WoP + (size_t)n0*256, 256, 256, ls, acc);
  const int tid=threadIdx.x, wave=tid>>6, lane=tid&63, wm=wave>>1, wn=wave&1;
  float lse_r[4][4], lo_r[4][4];
#pragma unroll
  for (int mi=0;mi<4;mi++)
#pragma unroll
    for (int q=0;q<4;q++){
      const int r = wm*64 + mi*16 + (lane>>4)*4 + q;
      lse_r[mi][q] = LSE_all[(size_t)t*NB + r];
      lo_r[mi][q]  = 1.f - pcb_all[(size_t)t*NB + r];
    }
#pragma unroll
  for (int mi=0;mi<4;mi++)
#pragma unroll
    for (int nj=0;nj<4;nj++){
      const int c = n0 + wn*64 + nj*16 + (lane&15);
      if (c >= NV) continue;
#pragma unroll
      for (int q=0;q<4;q++){
        const int r = wm*64 + mi*16 + (lane>>4)*4 + q;
        out[((size_t)r*NT + t)*OUTW + c] = __logf(lo_r[mi][q]*__expf(acc[mi][nj][q]-lse_r[mi][q]) + 1e-12f);
      }
    }
}

__global__ __launch_bounds__(256) void kB_copy(const float* __restrict__ pcb_all, const float* __restrict__ attn_all,
    float* __restrict__ out){
  const int total = NT*NB*NL;
  for (int idx = blockIdx.x*256 + threadIdx.x; idx < total; idx += gridDim.x*256){
    int t = idx / (NB*NL);
    int rem = idx - t*(NB*NL);
    int b = rem / NL, l = rem - b*NL;
    float pc = pcb_all[(size_t)t*NB + b];
    float av = attn_all[((size_t)t*NB + b)*NL + l];
    out[((size_t)b*NT + t)*OUTW + NV + l] = __logf(pc*av + 1e-12f);
  }
}

// ---------------- launch ----------------

extern "C" void kernel_launch(void* const* d_in, const int* in_sizes, int n_in,
                              void* d_out, int out_size, void* d_ws, size_t ws_size,
                              hipStream_t stream){
  const float* enc   = (const float*)d_in[0];
  const float* s_in  = (const float*)d_in[1];
  const int*   src   = (const int*)d_in[2];
  const int*   tgt   = (const int*)d_in[3];
  const float* embed = (const float*)d_in[4];
  const float* W_ih  = (const float*)d_in[5];
  const float* b_ih  = (const float*)d_in[6];
  const float* W_hh  = (const float*)d_in[7];
  const float* b_hh  = (const float*)d_in[8];
  const float* attWh = (const float*)d_in[9];
  const float* attWs = (const float*)d_in[10];
  const float* attb  = (const float*)d_in[11];
  const float* attv  = (const float*)d_in[12];
  const float* copyW = (const float*)d_in[13];
  const float* copyb = (const float*)d_in[14];
  const float* readW = (const float*)d_in[15];
  const float* readb = (const float*)d_in[16];
  const float* readWo= (const float*)d_in[17];
  float* out = (float*)d_out;
  (void)in_sizes; (void)n_in; (void)out_size; (void)ws_size;

  char* wsp = (char*)d_ws;
  size_t off = 0;
  auto alloc = [&](size_t bytes)->char*{ char* p = wsp + off; off = (off + bytes + 255) & ~(size_t)255; return p; };
  u16* enc_bf    = (u16*)alloc((size_t)NB*NL*NHE*2);
  u8*  encT8     = (u8*)alloc((size_t)NB*NHE*NL);
  u8*  eproj8    = (u8*)alloc((size_t)NB*NL*NA);
  u16* attWh_bf  = (u16*)alloc((size_t)NA*NHE*2);
  u8*  Wsb8      = (u8*)alloc((size_t)NA*NHD);
  u16* W1        = (u16*)alloc((size_t)N1*K1*2);
  u16* W2        = (u16*)alloc((size_t)512*K1*2);
  u16* Wemb      = (u16*)alloc((size_t)NW*KE*2);
  u16* Xemb      = (u16*)alloc((size_t)NT*NB*KE*2);
  u16* WoP       = (u16*)alloc((size_t)NVP*256*2);
  float* gre     = (float*)alloc((size_t)NT*NB*NW*4);
  float* gA      = (float*)alloc((size_t)NB*N1*4);
  float* gB      = (float*)alloc((size_t)NB*N1*4);
  u16* x1A       = (u16*)alloc((size_t)(NT+1)*NB*K1*2);
  float* sbufA   = (float*)alloc((size_t)NB*NHD*4);
  float* sbufB   = (float*)alloc((size_t)NB*NHD*4);
  float* e_buf   = (float*)alloc((size_t)4*NB*NL*4);
  float* attn_all= (float*)alloc((size_t)NT*NB*NL*4);
  float* ctx_ws  = (float*)alloc((size_t)NB*NHE*4);
  u16* mbf_all   = (u16*)alloc((size_t)NT*NB*256*2);
  float* parts   = (float*)alloc((size_t)NT*NB*160*4);
  float* LSE_all = (float*)alloc((size_t)NT*NB*4);
  float* pcb_all = (float*)alloc((size_t)NT*NB*4);
  u32* slots     = (u32*)alloc((size_t)NBLK*4);
  u32* gen       = (u32*)alloc((size_t)64*64);

  hipMemsetAsync(slots, 0, (size_t)NBLK*4, stream);
  hipMemsetAsync(gen,   0, (size_t)64*64, stream);

  k_conv_flat<<<4096,256,0,stream>>>(enc, enc_bf, (long)NB*NL*NHE);
  k_transpose<<<dim3(16,128),512,0,stream>>>(enc, encT8);
  k_conv_flat<<<1024,256,0,stream>>>(attWh, attWh_bf, (long)NA*NHE);
  k_conv_fp8<<<1024,256,0,stream>>>(attWs, Wsb8, (long)NA*NHD);
  k_build_w1<<<8192,256,0,stream>>>(W_hh, W_ih, W1);
  k_build_w2<<<2048,256,0,stream>>>(readW, W2);
  k_build_wemb<<<2560,256,0,stream>>>(W_ih, readW, Wemb);
  k_build_xemb<<<4800,256,0,stream>>>(tgt, embed, Xemb);
  k_convpad<<<2048,256,0,stream>>>(readWo, WoP, NV, 256, 256, (long)NVP*256);
  k_init<<<512,256,0,stream>>>(s_in, sbufA, x1A);
  k_encproj<<<dim3(4,400),256,0,stream>>>(enc_bf, attWh_bf, eproj8);
  k_gemm_emb<<<dim3(16,30),256,0,stream>>>(Xemb, Wemb, gre);

  KP kp;
  kp.bih = b_ih; kp.bhh = b_hh; kp.attb = attb; kp.attv = attv;
  kp.copyW = copyW; kp.copyb = copyb;
  kp.src = src;
  kp.Wsb8 = Wsb8; kp.eproj8 = eproj8; kp.encT8 = encT8; kp.W1 = W1;
  kp.gre = gre;
  kp.gA = gA; kp.gB = gB; kp.sbufA = sbufA; kp.sbufB = sbufB;
  kp.e = e_buf; kp.ctx_ws = ctx_ws; kp.attn_all = attn_all; kp.pcb_all = pcb_all;
  kp.x1A = x1A;
  kp.slots = slots; kp.gen = gen;

  k_persist<<<NBLK,256,0,stream>>>(kp);

  kB_read<<<dim3(4,NT),256,0,stream>>>(x1A, W2, gre, readb, mbf_all);
  kB_lse<<<dim3(157,NT),256,0,stream>>>(mbf_all, WoP, parts);
  kB_lsered<<<NT*NB,256,0,stream>>>(parts, LSE_all);
  kB_out2<<<dim3(157,NT),256,0,stream>>>(mbf_all, WoP, LSE_all, pcb_all, out);
  kB_copy<<<1024,256,0,stream>>>(pcb_all, attn_all, out);
}